// Round 5
// baseline (762.020 us; speedup 1.0000x reference)
//
#include <hip/hip_runtime.h>
#include <math.h>

// Problem constants
#define C_DIM 64
#define T_DIM 256
#define F_DIM 128
#define DI    128
#define DS    16
#define CK    16     // tokens per chunk in fused mamba kernel

__device__ __forceinline__ float silu_f(float v){ return v / (1.0f + __expf(-v)); }

// ---------------------------------------------------------------------------
// x (1,64,256,128) [c,t,f] -> xt (f,t,c), one block per t
// ---------------------------------------------------------------------------
__global__ __launch_bounds__(256) void k_transpose_in(const float* __restrict__ x,
                                                      float* __restrict__ xt){
  __shared__ float tile[64][133];
  const int t = blockIdx.x;
  {
    const int fi = threadIdx.x & 127, cg = threadIdx.x >> 7;  // cg 0..1
    for(int c = cg*32; c < cg*32 + 32; ++c)
      tile[c][fi] = x[(size_t)c*32768 + (size_t)t*128 + fi];
  }
  __syncthreads();
  {
    const int ci = threadIdx.x & 63, fg = threadIdx.x >> 6;   // fg 0..3
    for(int f = fg*32; f < fg*32 + 32; ++f)
      xt[(size_t)f*16384 + (size_t)t*64 + ci] = tile[ci][f];
  }
}

// ---------------------------------------------------------------------------
// Fused per-sequence Mamba mixer. One workgroup = (dir, sequence n).
// src token (n,l): src[n*sn + l_eff*sl + c], c contiguous.
// Writes mamba output (no residual) to obuf[(dir*32768 + n*L + l_orig)*64 + o].
// ---------------------------------------------------------------------------
__global__ __launch_bounds__(256, 2) void k_mamba(
    const float* __restrict__ src, int N, int L, long long sn, long long sl,
    int pbase,
    const float* __restrict__ norm_w,   const float* __restrict__ in_proj_w,
    const float* __restrict__ conv_w,   const float* __restrict__ conv_b,
    const float* __restrict__ x_proj_w, const float* __restrict__ dt_proj_w,
    const float* __restrict__ dt_proj_b,const float* __restrict__ A_log,
    const float* __restrict__ Dp,       const float* __restrict__ out_proj_w,
    float* __restrict__ obuf)
{
  __shared__ float u_s[CK][68];        // normalized input (CK x 64)
  __shared__ float x_s[CK+3][132];     // conv input, rows 0..2 = history
  __shared__ float z_s[CK][132];       // gate
  __shared__ float xc_s[CK][132];      // conv out -> later y -> later y*silu(z)
  __shared__ float dt_s[CK][132];
  __shared__ float dtr_s[CK][4];
  __shared__ float B_s[CK][20];
  __shared__ float C_s[CK][20];
  __shared__ float w_xp[36*132];       // x_proj_w rows padded to 132
  __shared__ float w_cv[512];
  __shared__ float b_cv[128];
  __shared__ float w_dt[512];
  __shared__ float b_dt[128];
  __shared__ float dvec[128];
  __shared__ float nw[64];

  const int tid = threadIdx.x;
  const int bid = blockIdx.x;
  const int dir = (bid >= N) ? 1 : 0;
  const int n   = dir ? (bid - N) : bid;
  const int p   = pbase + dir;

  // stage per-param-set small weights into LDS
  for(int i = tid; i < 36*128; i += 256){
    int o = i >> 7, k = i & 127;
    w_xp[o*132 + k] = x_proj_w[p*4608 + i];
  }
  for(int i = tid; i < 512; i += 256){ w_cv[i] = conv_w[p*512 + i]; w_dt[i] = dt_proj_w[p*512 + i]; }
  if(tid < 128){ b_cv[tid] = conv_b[p*128 + tid]; b_dt[tid] = dt_proj_b[p*128 + tid]; dvec[tid] = Dp[p*128 + tid]; }
  if(tid < 64) nw[tid] = norm_w[p*64 + tid];
  for(int i = tid; i < 3*128; i += 256){ x_s[i >> 7][i & 127] = 0.0f; }  // zero conv history

  // scan state: thread pair per channel d; each thread owns 8 of 16 states
  const int d_own = tid >> 1;
  const int sh    = (tid & 1) * 8;
  float A_r[8], h[8];
  #pragma unroll
  for(int i = 0; i < 8; ++i){
    A_r[i] = -__expf(A_log[p*2048 + d_own*16 + sh + i]) * 1.44269504f;  // A * log2(e)
    h[i] = 0.0f;
  }
  __syncthreads();

  const float* Win  = in_proj_w  + p*16384;
  const float* Wout = out_proj_w + p*8192;

  for(int c0 = 0; c0 < L; c0 += CK){
    // P9: shift conv history (rows CK..CK+2 of previous chunk -> rows 0..2)
    if(c0 > 0){
      for(int i = tid; i < 3*128; i += 256){
        int r = i >> 7, ch = i & 127;
        x_s[r][ch] = x_s[CK + r][ch];
      }
    }
    // P1: load + rmsnorm. 16 tokens x 16 threads; thread covers 4 channels.
    {
      const int g = tid >> 4, j = tid & 15, c4 = j*4;
      const int l = c0 + g;
      const int lo = dir ? (L - 1 - l) : l;
      const float4 v = *(const float4*)(src + (size_t)n*sn + (size_t)lo*sl + c4);
      float ssq = v.x*v.x + v.y*v.y + v.z*v.z + v.w*v.w;
      ssq += __shfl_xor(ssq, 1); ssq += __shfl_xor(ssq, 2);
      ssq += __shfl_xor(ssq, 4); ssq += __shfl_xor(ssq, 8);
      const float sc = rsqrtf(ssq * (1.0f/64.0f) + 1e-5f);
      u_s[g][c4+0] = v.x * sc * nw[c4+0];
      u_s[g][c4+1] = v.y * sc * nw[c4+1];
      u_s[g][c4+2] = v.z * sc * nw[c4+2];
      u_s[g][c4+3] = v.w * sc * nw[c4+3];
    }
    __syncthreads();

    // P2: in_proj 64 -> 256. thread = output o, acc over 16 tokens, k hoisted.
    {
      const int o = tid;
      float acc[CK];
      #pragma unroll
      for(int l = 0; l < CK; ++l) acc[l] = 0.0f;
      const float4* wr = (const float4*)(Win + o*64);
      #pragma unroll 4
      for(int k4 = 0; k4 < 16; ++k4){
        const float4 w = wr[k4];
        #pragma unroll
        for(int l = 0; l < CK; ++l){
          const float4 a = *(const float4*)&u_s[l][k4*4];
          acc[l] += w.x*a.x + w.y*a.y + w.z*a.z + w.w*a.w;
        }
      }
      if(o < 128){
        #pragma unroll
        for(int l = 0; l < CK; ++l) x_s[3 + l][o] = acc[l];
      } else {
        #pragma unroll
        for(int l = 0; l < CK; ++l) z_s[l][o - 128] = acc[l];
      }
    }
    __syncthreads();

    // P3: causal depthwise conv(4) + bias + silu
    {
      const int g = tid >> 4, j = tid & 15;
      #pragma unroll
      for(int i = 0; i < 8; ++i){
        const int ch = j + 16*i;
        float a = b_cv[ch];
        a += w_cv[ch*4+0] * x_s[g+0][ch];
        a += w_cv[ch*4+1] * x_s[g+1][ch];
        a += w_cv[ch*4+2] * x_s[g+2][ch];
        a += w_cv[ch*4+3] * x_s[g+3][ch];
        xc_s[g][ch] = silu_f(a);
      }
    }
    __syncthreads();

    // P4: x_proj 128 -> 36 (dt_r 0..3 | B 4..19 | C 20..35)
    {
      const int g = tid >> 4, j = tid & 15;
      #pragma unroll
      for(int rep = 0; rep < 3; ++rep){
        const int o36 = j + rep*16;
        if(o36 < 36){
          const float4* wr = (const float4*)&w_xp[o36*132];
          const float4* xr = (const float4*)&xc_s[g][0];
          float a = 0.0f;
          #pragma unroll
          for(int k4 = 0; k4 < 32; ++k4){
            const float4 w = wr[k4], xv = xr[k4];
            a += w.x*xv.x + w.y*xv.y + w.z*xv.z + w.w*xv.w;
          }
          if(o36 < 4)       dtr_s[g][o36] = a;
          else if(o36 < 20) B_s[g][o36 - 4] = a;
          else              C_s[g][o36 - 20] = a;
        }
      }
    }
    __syncthreads();

    // P5: dt_proj 4 -> 128 + bias + softplus
    {
      const int g = tid >> 4, j = tid & 15;
      const float r0 = dtr_s[g][0], r1 = dtr_s[g][1], r2 = dtr_s[g][2], r3 = dtr_s[g][3];
      #pragma unroll
      for(int i = 0; i < 8; ++i){
        const int d = j + 16*i;
        float a = b_dt[d] + w_dt[d*4+0]*r0 + w_dt[d*4+1]*r1 + w_dt[d*4+2]*r2 + w_dt[d*4+3]*r3;
        dt_s[g][d] = fmaxf(a, 0.0f) + log1pf(__expf(-fabsf(a)));  // stable softplus
      }
    }
    __syncthreads();

    // P6: sequential selective scan over the chunk (no barriers inside).
    // y (= ys + xconv*Dp) overwrites xc_s in place (read-before-write per pair).
    for(int l = 0; l < CK; ++l){
      const float dtv = dt_s[l][d_own];
      const float xv  = xc_s[l][d_own];
      const float4 b0 = *(const float4*)&B_s[l][sh];
      const float4 b1 = *(const float4*)&B_s[l][sh + 4];
      const float4 g0 = *(const float4*)&C_s[l][sh];
      const float4 g1 = *(const float4*)&C_s[l][sh + 4];
      const float bb[8] = {b0.x,b0.y,b0.z,b0.w,b1.x,b1.y,b1.z,b1.w};
      const float cc[8] = {g0.x,g0.y,g0.z,g0.w,g1.x,g1.y,g1.z,g1.w};
      const float dx = dtv * xv;
      float yp = 0.0f;
      #pragma unroll
      for(int i = 0; i < 8; ++i){
        h[i] = exp2f(dtv * A_r[i]) * h[i] + dx * bb[i];
        yp += h[i] * cc[i];
      }
      const float yo = yp + __shfl_xor(yp, 1);
      if((tid & 1) == 0) xc_s[l][d_own] = yo + xv * dvec[d_own];
    }
    __syncthreads();

    // P7: y *= silu(z)
    {
      const int g = tid >> 4, j = tid & 15;
      #pragma unroll
      for(int i = 0; i < 8; ++i){
        const int ch = j + 16*i;
        xc_s[g][ch] = xc_s[g][ch] * silu_f(z_s[g][ch]);
      }
    }
    __syncthreads();

    // P8: out_proj 128 -> 64, store to obuf (logical/unflipped order)
    {
      const int o = tid & 63, lg = tid >> 6;   // 4 token-groups of 4
      const float4* wr = (const float4*)(Wout + o*128);
      float acc[4] = {0,0,0,0};
      #pragma unroll 4
      for(int k4 = 0; k4 < 32; ++k4){
        const float4 w = wr[k4];
        #pragma unroll
        for(int li = 0; li < 4; ++li){
          const float4 a = *(const float4*)&xc_s[lg*4 + li][k4*4];
          acc[li] += w.x*a.x + w.y*a.y + w.z*a.z + w.w*a.w;
        }
      }
      #pragma unroll
      for(int li = 0; li < 4; ++li){
        const int l = c0 + lg*4 + li;
        const int lo = dir ? (L - 1 - l) : l;
        obuf[((size_t)dir*32768 + (size_t)n*L + lo)*64 + o] = acc[li];
      }
    }
    __syncthreads();
  }
}

// ---------------------------------------------------------------------------
// xt2 = xt + (of+xt)@tlin[0:64] + (ob+xt)@tlin[64:128] + tlin_b
// token tk = f*256 + t; 4 tokens per block, lane = output channel o.
// ---------------------------------------------------------------------------
__global__ __launch_bounds__(256) void k_comb_time(
    const float* __restrict__ xt, const float* __restrict__ obuf,
    const float* __restrict__ tlin_w, const float* __restrict__ tlin_b,
    float* __restrict__ xt2)
{
  __shared__ float xs[4][68], fs[4][68], bs[4][68];
  const int tg = threadIdx.x >> 6, o = threadIdx.x & 63;
  const int tk = blockIdx.x*4 + tg;
  xs[tg][o] = xt[(size_t)tk*64 + o];
  fs[tg][o] = obuf[(size_t)tk*64 + o];
  bs[tg][o] = obuf[(size_t)(32768 + tk)*64 + o];
  __syncthreads();
  float acc = xs[tg][o] + tlin_b[o];
  #pragma unroll 4
  for(int i = 0; i < 64; ++i){
    const float xv = xs[tg][i];
    acc += (fs[tg][i] + xv) * tlin_w[i*64 + o]
         + (bs[tg][i] + xv) * tlin_w[(64 + i)*64 + o];
  }
  xt2[(size_t)tk*64 + o] = acc;
}

// ---------------------------------------------------------------------------
// Final: xf2 = xf + (of+xf)@flin[0:64] + (ob+xf)@flin[64:128] + flin_b,
// then transposed store out[c,t,f]. One block per t; thread pair per f.
// ---------------------------------------------------------------------------
__global__ __launch_bounds__(256) void k_final(
    const float* __restrict__ xt2, const float* __restrict__ obuf,
    const float* __restrict__ flin_w, const float* __restrict__ flin_b,
    float* __restrict__ out)
{
  __shared__ float res_s[128][68];
  const int t = blockIdx.x, tid = threadIdx.x;
  const int f = tid >> 1, half = tid & 1, cbase = half*32;

  const float4* xr = (const float4*)(xt2  + (size_t)f*16384 + (size_t)t*64);
  const float4* fr = (const float4*)(obuf + ((size_t)t*128 + f)*64);
  const float4* br = (const float4*)(obuf + ((size_t)32768 + (size_t)t*128 + f)*64);

  float res[32];
  {
    const float4* fb = (const float4*)(flin_b + cbase);
    #pragma unroll
    for(int q = 0; q < 8; ++q){
      const float4 xv = xr[(cbase >> 2) + q], b = fb[q];
      res[q*4+0] = xv.x + b.x; res[q*4+1] = xv.y + b.y;
      res[q*4+2] = xv.z + b.z; res[q*4+3] = xv.w + b.w;
    }
  }
  for(int i4 = 0; i4 < 16; ++i4){
    const float4 xv4 = xr[i4], of4 = fr[i4], ob4 = br[i4];
    const float af[4] = {of4.x + xv4.x, of4.y + xv4.y, of4.z + xv4.z, of4.w + xv4.w};
    const float ab[4] = {ob4.x + xv4.x, ob4.y + xv4.y, ob4.z + xv4.z, ob4.w + xv4.w};
    #pragma unroll
    for(int ii = 0; ii < 4; ++ii){
      const int i = i4*4 + ii;
      const float4* F0 = (const float4*)(flin_w + i*64 + cbase);
      const float4* F1 = (const float4*)(flin_w + (64 + i)*64 + cbase);
      #pragma unroll
      for(int q = 0; q < 8; ++q){
        const float4 w0 = F0[q], w1 = F1[q];
        res[q*4+0] += af[ii]*w0.x + ab[ii]*w1.x;
        res[q*4+1] += af[ii]*w0.y + ab[ii]*w1.y;
        res[q*4+2] += af[ii]*w0.z + ab[ii]*w1.z;
        res[q*4+3] += af[ii]*w0.w + ab[ii]*w1.w;
      }
    }
  }
  #pragma unroll
  for(int c = 0; c < 32; ++c) res_s[f][cbase + c] = res[c];
  __syncthreads();
  {
    const int fi = tid & 127, cq = tid >> 7;
    for(int c = cq*32; c < cq*32 + 32; ++c)
      out[(size_t)c*32768 + (size_t)t*128 + fi] = res_s[fi][c];
  }
}

// ---------------------------------------------------------------------------
extern "C" void kernel_launch(void* const* d_in, const int* in_sizes, int n_in,
                              void* d_out, int out_size, void* d_ws, size_t ws_size,
                              hipStream_t stream){
  (void)in_sizes; (void)n_in; (void)out_size; (void)ws_size;
  const float* x         = (const float*)d_in[0];
  const float* norm_w    = (const float*)d_in[1];
  const float* in_proj_w = (const float*)d_in[2];
  const float* conv_w    = (const float*)d_in[3];
  const float* conv_b    = (const float*)d_in[4];
  const float* x_proj_w  = (const float*)d_in[5];
  const float* dt_proj_w = (const float*)d_in[6];
  const float* dt_proj_b = (const float*)d_in[7];
  const float* A_log     = (const float*)d_in[8];
  const float* Dp        = (const float*)d_in[9];
  const float* out_proj_w= (const float*)d_in[10];
  const float* tlin_w    = (const float*)d_in[11];
  const float* tlin_b    = (const float*)d_in[12];
  const float* flin_w    = (const float*)d_in[13];
  const float* flin_b    = (const float*)d_in[14];
  float* out = (float*)d_out;

  float* xt_buf = (float*)d_ws;                 // 2M floats  (8 MB)   [f][t][c]
  float* obuf   = xt_buf + (size_t)(1u << 21);  // 4M floats  (16 MB)  [dir][token][64]
  float* xt2    = obuf   + (size_t)(1u << 22);  // 2M floats  (8 MB)   [f][t][c]

  hipLaunchKernelGGL(k_transpose_in, dim3(256), dim3(256), 0, stream, x, xt_buf);

  // time axis: N=128 sequences (f), L=256 (t); params P0 (fwd), P1 (bwd)
  hipLaunchKernelGGL(k_mamba, dim3(256), dim3(256), 0, stream,
      xt_buf, 128, 256, (long long)16384, (long long)64, 0,
      norm_w, in_proj_w, conv_w, conv_b, x_proj_w, dt_proj_w, dt_proj_b,
      A_log, Dp, out_proj_w, obuf);

  hipLaunchKernelGGL(k_comb_time, dim3(8192), dim3(256), 0, stream,
      xt_buf, obuf, tlin_w, tlin_b, xt2);

  // freq axis: N=256 sequences (t), L=128 (f); params P2 (fwd), P3 (bwd)
  hipLaunchKernelGGL(k_mamba, dim3(512), dim3(256), 0, stream,
      xt2, 256, 128, (long long)64, (long long)16384, 2,
      norm_w, in_proj_w, conv_w, conv_b, x_proj_w, dt_proj_w, dt_proj_b,
      A_log, Dp, out_proj_w, obuf);

  hipLaunchKernelGGL(k_final, dim3(256), dim3(256), 0, stream,
      xt2, obuf, flin_w, flin_b, out);
}

// Round 8
// 500.778 us; speedup vs baseline: 1.5217x; 1.5217x over previous
//
#include <hip/hip_runtime.h>
#include <math.h>

// Problem constants
#define C_DIM 64
#define T_DIM 256
#define F_DIM 128
#define DI    128
#define DS    16
#define CK    16     // tokens per chunk in fused mamba kernel

typedef __attribute__((ext_vector_type(8))) short bf16x8;  // 8 bf16 = 4 VGPRs
typedef __attribute__((ext_vector_type(4))) float f32x4;   // MFMA C/D

__device__ __forceinline__ float silu_f(float v){ return v / (1.0f + __expf(-v)); }

__device__ __forceinline__ unsigned short f2bf(float f){
  union{float f; unsigned u;} v; v.f = f;
  unsigned r = v.u + 0x7FFFu + ((v.u >> 16) & 1u);   // RTNE
  return (unsigned short)(r >> 16);
}

// ---------------------------------------------------------------------------
// Convert in_proj_w (4x256x64) and out_proj_w (4x64x128) to bf16 scratch.
// wbuf[0..65536) = in_proj bf16, wbuf[65536..98304) = out_proj bf16.
// ---------------------------------------------------------------------------
__global__ __launch_bounds__(256) void k_prep(const float* __restrict__ ipw,
                                              const float* __restrict__ opw,
                                              unsigned short* __restrict__ wbuf){
  const int i = blockIdx.x*256 + threadIdx.x;
  if(i < 65536)       wbuf[i] = f2bf(ipw[i]);
  else if(i < 98304)  wbuf[i] = f2bf(opw[i - 65536]);
}

// ---------------------------------------------------------------------------
// x (1,64,256,128) [c,t,f] -> xt (f,t,c), one block per t
// ---------------------------------------------------------------------------
__global__ __launch_bounds__(256) void k_transpose_in(const float* __restrict__ x,
                                                      float* __restrict__ xt){
  __shared__ float tile[64][133];
  const int t = blockIdx.x;
  {
    const int fi = threadIdx.x & 127, cg = threadIdx.x >> 7;  // cg 0..1
    for(int c = cg*32; c < cg*32 + 32; ++c)
      tile[c][fi] = x[(size_t)c*32768 + (size_t)t*128 + fi];
  }
  __syncthreads();
  {
    const int ci = threadIdx.x & 63, fg = threadIdx.x >> 6;   // fg 0..3
    for(int f = fg*32; f < fg*32 + 32; ++f)
      xt[(size_t)f*16384 + (size_t)t*64 + ci] = tile[ci][f];
  }
}

// ---------------------------------------------------------------------------
// Fused per-sequence Mamba mixer. One workgroup = (dir, sequence n).
// in_proj / out_proj on bf16 MFMA (weights pre-converted in wbf);
// x_proj / conv / scan / gating stay fp32 VALU.
// ---------------------------------------------------------------------------
__global__ __launch_bounds__(256, 2) void k_mamba(
    const float* __restrict__ src, int N, int L, long long sn, long long sl,
    int pbase,
    const float* __restrict__ norm_w,   const unsigned short* __restrict__ wbf,
    const float* __restrict__ conv_w,   const float* __restrict__ conv_b,
    const float* __restrict__ x_proj_w, const float* __restrict__ dt_proj_w,
    const float* __restrict__ dt_proj_b,const float* __restrict__ A_log,
    const float* __restrict__ Dp,       float* __restrict__ obuf)
{
  __shared__ __align__(16) unsigned short u_bf[CK][64];   // normalized input, bf16
  __shared__ float x_s[CK+3][132];     // conv input, rows 0..2 = history
  __shared__ float z_s[CK][132];       // gate
  __shared__ float xc_s[CK][132];      // conv out -> y (pre-gate) after scan
  __shared__ float dt_s[CK][132];
  __shared__ float dtr_s[CK][4];
  __shared__ float B_s[CK][20];
  __shared__ float C_s[CK][20];
  __shared__ __align__(16) unsigned short y_bf[CK][128];  // gated y, bf16 (P8 input)
  __shared__ float y_out[CK][68];      // out_proj result
  __shared__ float w_xp[36*132];       // x_proj_w rows padded to 132
  __shared__ float w_cv[512];
  __shared__ float b_cv[128];
  __shared__ float w_dt[512];
  __shared__ float b_dt[128];
  __shared__ float dvec[128];
  __shared__ float nw[64];

  const int tid = threadIdx.x;
  const int bid = blockIdx.x;
  const int dir = (bid >= N) ? 1 : 0;
  const int n   = dir ? (bid - N) : bid;
  const int p   = pbase + dir;

  const int lane = tid & 63;
  const int wv   = tid >> 6;          // wave 0..3
  const int fr   = lane & 15;         // fragment row/col (token or o within tile)
  const int fk   = (lane >> 4) << 3;  // k-offset within 32-slice: {0,8,16,24}

  // stage per-param-set small weights into LDS
  for(int i = tid; i < 36*128; i += 256){
    int o = i >> 7, k = i & 127;
    w_xp[o*132 + k] = x_proj_w[p*4608 + i];
  }
  for(int i = tid; i < 512; i += 256){ w_cv[i] = conv_w[p*512 + i]; w_dt[i] = dt_proj_w[p*512 + i]; }
  if(tid < 128){ b_cv[tid] = conv_b[p*128 + tid]; b_dt[tid] = dt_proj_b[p*128 + tid]; dvec[tid] = Dp[p*128 + tid]; }
  if(tid < 64) nw[tid] = norm_w[p*64 + tid];
  for(int i = tid; i < 3*128; i += 256){ x_s[i >> 7][i & 127] = 0.0f; }  // zero conv history

  // MFMA weight fragments (held in registers for the whole kernel).
  // in_proj: A = Win (256x64). wave wv owns o-tiles 4wv..4wv+3 (o = 64wv..64wv+63).
  // out_proj: A = Wout (64x128). wave wv owns o2-tile wv (o2 = 16wv..16wv+15).
  const unsigned short* WinB  = wbf + (size_t)p*16384;          // [256][64]
  const unsigned short* WoutB = wbf + 65536 + (size_t)p*8192;   // [64][128]
  bf16x8 aW[4][2];
  #pragma unroll
  for(int ot = 0; ot < 4; ++ot)
    #pragma unroll
    for(int kh = 0; kh < 2; ++kh)
      aW[ot][kh] = *(const bf16x8*)(WinB + (wv*64 + ot*16 + fr)*64 + kh*32 + fk);
  bf16x8 aO[4];
  #pragma unroll
  for(int kc = 0; kc < 4; ++kc)
    aO[kc] = *(const bf16x8*)(WoutB + (wv*16 + fr)*128 + kc*32 + fk);

  // scan state: thread pair per channel d; each thread owns 8 of 16 states
  const int d_own = tid >> 1;
  const int sh    = (tid & 1) * 8;
  float A_r[8], h[8];
  #pragma unroll
  for(int i = 0; i < 8; ++i){
    A_r[i] = -__expf(A_log[p*2048 + d_own*16 + sh + i]) * 1.44269504f;  // A * log2(e)
    h[i] = 0.0f;
  }
  __syncthreads();

  for(int c0 = 0; c0 < L; c0 += CK){
    // P9: shift conv history (rows CK..CK+2 of previous chunk -> rows 0..2)
    if(c0 > 0){
      for(int i = tid; i < 3*128; i += 256){
        int r = i >> 7, ch = i & 127;
        x_s[r][ch] = x_s[CK + r][ch];
      }
    }
    // P1: load + rmsnorm -> u_bf (bf16). 16 tokens x 16 threads, 4 ch each.
    {
      const int g = tid >> 4, j = tid & 15, c4 = j*4;
      const int l = c0 + g;
      const int lo = dir ? (L - 1 - l) : l;
      const float4 v = *(const float4*)(src + (size_t)n*sn + (size_t)lo*sl + c4);
      float ssq = v.x*v.x + v.y*v.y + v.z*v.z + v.w*v.w;
      ssq += __shfl_xor(ssq, 1); ssq += __shfl_xor(ssq, 2);
      ssq += __shfl_xor(ssq, 4); ssq += __shfl_xor(ssq, 8);
      const float sc = rsqrtf(ssq * (1.0f/64.0f) + 1e-5f);
      ushort4 pk;
      pk.x = f2bf(v.x * sc * nw[c4+0]);
      pk.y = f2bf(v.y * sc * nw[c4+1]);
      pk.z = f2bf(v.z * sc * nw[c4+2]);
      pk.w = f2bf(v.w * sc * nw[c4+3]);
      *(ushort4*)&u_bf[g][c4] = pk;
    }
    __syncthreads();

    // P2: in_proj 64 -> 256 via MFMA. D: row=(lane>>4)*4+r (o), col=fr (token).
    {
      const bf16x8 b0 = *(const bf16x8*)&u_bf[fr][fk];
      const bf16x8 b1 = *(const bf16x8*)&u_bf[fr][32 + fk];
      #pragma unroll
      for(int ot = 0; ot < 4; ++ot){
        f32x4 acc = {0.f, 0.f, 0.f, 0.f};
        acc = __builtin_amdgcn_mfma_f32_16x16x32_bf16(aW[ot][0], b0, acc, 0, 0, 0);
        acc = __builtin_amdgcn_mfma_f32_16x16x32_bf16(aW[ot][1], b1, acc, 0, 0, 0);
        const int ob = wv*64 + ot*16 + ((lane >> 4) << 2);
        if(wv < 2){
          #pragma unroll
          for(int r = 0; r < 4; ++r) x_s[3 + fr][ob + r] = acc[r];
        } else {
          #pragma unroll
          for(int r = 0; r < 4; ++r) z_s[fr][ob + r - 128] = acc[r];
        }
      }
    }
    __syncthreads();

    // P3: causal depthwise conv(4) + bias + silu (fp32)
    {
      const int g = tid >> 4, j = tid & 15;
      #pragma unroll
      for(int i = 0; i < 8; ++i){
        const int ch = j + 16*i;
        float a = b_cv[ch];
        a += w_cv[ch*4+0] * x_s[g+0][ch];
        a += w_cv[ch*4+1] * x_s[g+1][ch];
        a += w_cv[ch*4+2] * x_s[g+2][ch];
        a += w_cv[ch*4+3] * x_s[g+3][ch];
        xc_s[g][ch] = silu_f(a);
      }
    }
    __syncthreads();

    // P4: x_proj 128 -> 36 (dt_r 0..3 | B 4..19 | C 20..35), fp32
    {
      const int g = tid >> 4, j = tid & 15;
      #pragma unroll
      for(int rep = 0; rep < 3; ++rep){
        const int o36 = j + rep*16;
        if(o36 < 36){
          const float4* wr = (const float4*)&w_xp[o36*132];
          const float4* xr = (const float4*)&xc_s[g][0];
          float a = 0.0f;
          #pragma unroll
          for(int k4 = 0; k4 < 32; ++k4){
            const float4 w = wr[k4], xv = xr[k4];
            a += w.x*xv.x + w.y*xv.y + w.z*xv.z + w.w*xv.w;
          }
          if(o36 < 4)       dtr_s[g][o36] = a;
          else if(o36 < 20) B_s[g][o36 - 4] = a;
          else              C_s[g][o36 - 20] = a;
        }
      }
    }
    __syncthreads();

    // P5: dt_proj 4 -> 128 + bias + softplus
    {
      const int g = tid >> 4, j = tid & 15;
      const float r0 = dtr_s[g][0], r1 = dtr_s[g][1], r2 = dtr_s[g][2], r3 = dtr_s[g][3];
      #pragma unroll
      for(int i = 0; i < 8; ++i){
        const int d = j + 16*i;
        float a = b_dt[d] + w_dt[d*4+0]*r0 + w_dt[d*4+1]*r1 + w_dt[d*4+2]*r2 + w_dt[d*4+3]*r3;
        dt_s[g][d] = fmaxf(a, 0.0f) + log1pf(__expf(-fabsf(a)));  // stable softplus
      }
    }
    __syncthreads();

    // P6: sequential selective scan over the chunk (no barriers inside).
    for(int l = 0; l < CK; ++l){
      const float dtv = dt_s[l][d_own];
      const float xv  = xc_s[l][d_own];
      const float4 b0 = *(const float4*)&B_s[l][sh];
      const float4 b1 = *(const float4*)&B_s[l][sh + 4];
      const float4 g0 = *(const float4*)&C_s[l][sh];
      const float4 g1 = *(const float4*)&C_s[l][sh + 4];
      const float bb[8] = {b0.x,b0.y,b0.z,b0.w,b1.x,b1.y,b1.z,b1.w};
      const float cc[8] = {g0.x,g0.y,g0.z,g0.w,g1.x,g1.y,g1.z,g1.w};
      const float dx = dtv * xv;
      float yp = 0.0f;
      #pragma unroll
      for(int i = 0; i < 8; ++i){
        h[i] = exp2f(dtv * A_r[i]) * h[i] + dx * bb[i];
        yp += h[i] * cc[i];
      }
      const float yo = yp + __shfl_xor(yp, 1);
      if((tid & 1) == 0) xc_s[l][d_own] = yo + xv * dvec[d_own];
    }
    __syncthreads();

    // P7: y = y * silu(z) -> y_bf (bf16, input of out_proj MFMA)
    {
      const int g = tid >> 4, j = tid & 15;
      #pragma unroll
      for(int i = 0; i < 8; ++i){
        const int ch = j + 16*i;
        y_bf[g][ch] = f2bf(xc_s[g][ch] * silu_f(z_s[g][ch]));
      }
    }
    __syncthreads();

    // P8: out_proj 128 -> 64 via MFMA. wave wv -> o2-tile wv.
    {
      f32x4 acc = {0.f, 0.f, 0.f, 0.f};
      #pragma unroll
      for(int kc = 0; kc < 4; ++kc){
        const bf16x8 b = *(const bf16x8*)&y_bf[fr][kc*32 + fk];
        acc = __builtin_amdgcn_mfma_f32_16x16x32_bf16(aO[kc], b, acc, 0, 0, 0);
      }
      const int o2 = wv*16 + ((lane >> 4) << 2);
      #pragma unroll
      for(int r = 0; r < 4; ++r) y_out[fr][o2 + r] = acc[r];
    }
    __syncthreads();

    // P8b: coalesced store to obuf (logical/unflipped order)
    {
      const int o = tid & 63, lg = tid >> 6;   // 4 token-groups of 4
      #pragma unroll
      for(int li = 0; li < 4; ++li){
        const int l = c0 + lg*4 + li;
        const int lo = dir ? (L - 1 - l) : l;
        obuf[((size_t)dir*32768 + (size_t)n*L + lo)*64 + o] = y_out[lg*4 + li][o];
      }
    }
    // no end-of-chunk barrier needed: next writes to u_bf/x_s[0..2] have had
    // their readers (this chunk's P2/P3) barrier-retired; y_out next written
    // only after next chunk's post-P7 barrier.
  }
}

// ---------------------------------------------------------------------------
// xt2 = xt + (of+xt)@tlin[0:64] + (ob+xt)@tlin[64:128] + tlin_b
// ---------------------------------------------------------------------------
__global__ __launch_bounds__(256) void k_comb_time(
    const float* __restrict__ xt, const float* __restrict__ obuf,
    const float* __restrict__ tlin_w, const float* __restrict__ tlin_b,
    float* __restrict__ xt2)
{
  __shared__ float xs[4][68], fs[4][68], bs[4][68];
  const int tg = threadIdx.x >> 6, o = threadIdx.x & 63;
  const int tk = blockIdx.x*4 + tg;
  xs[tg][o] = xt[(size_t)tk*64 + o];
  fs[tg][o] = obuf[(size_t)tk*64 + o];
  bs[tg][o] = obuf[(size_t)(32768 + tk)*64 + o];
  __syncthreads();
  float acc = xs[tg][o] + tlin_b[o];
  #pragma unroll 4
  for(int i = 0; i < 64; ++i){
    const float xv = xs[tg][i];
    acc += (fs[tg][i] + xv) * tlin_w[i*64 + o]
         + (bs[tg][i] + xv) * tlin_w[(64 + i)*64 + o];
  }
  xt2[(size_t)tk*64 + o] = acc;
}

// ---------------------------------------------------------------------------
// Final: xf2 = xf + (of+xf)@flin[0:64] + (ob+xf)@flin[64:128] + flin_b,
// then transposed store out[c,t,f]. One block per t; thread pair per f.
// ---------------------------------------------------------------------------
__global__ __launch_bounds__(256) void k_final(
    const float* __restrict__ xt2, const float* __restrict__ obuf,
    const float* __restrict__ flin_w, const float* __restrict__ flin_b,
    float* __restrict__ out)
{
  __shared__ float res_s[128][68];
  const int t = blockIdx.x, tid = threadIdx.x;
  const int f = tid >> 1, half = tid & 1, cbase = half*32;

  const float4* xr = (const float4*)(xt2  + (size_t)f*16384 + (size_t)t*64);
  const float4* fr = (const float4*)(obuf + ((size_t)t*128 + f)*64);
  const float4* br = (const float4*)(obuf + ((size_t)32768 + (size_t)t*128 + f)*64);

  float res[32];
  {
    const float4* fb = (const float4*)(flin_b + cbase);
    #pragma unroll
    for(int q = 0; q < 8; ++q){
      const float4 xv = xr[(cbase >> 2) + q], b = fb[q];
      res[q*4+0] = xv.x + b.x; res[q*4+1] = xv.y + b.y;
      res[q*4+2] = xv.z + b.z; res[q*4+3] = xv.w + b.w;
    }
  }
  for(int i4 = 0; i4 < 16; ++i4){
    const float4 xv4 = xr[i4], of4 = fr[i4], ob4 = br[i4];
    const float af[4] = {of4.x + xv4.x, of4.y + xv4.y, of4.z + xv4.z, of4.w + xv4.w};
    const float ab[4] = {ob4.x + xv4.x, ob4.y + xv4.y, ob4.z + xv4.z, ob4.w + xv4.w};
    #pragma unroll
    for(int ii = 0; ii < 4; ++ii){
      const int i = i4*4 + ii;
      const float4* F0 = (const float4*)(flin_w + i*64 + cbase);
      const float4* F1 = (const float4*)(flin_w + (64 + i)*64 + cbase);
      #pragma unroll
      for(int q = 0; q < 8; ++q){
        const float4 w0 = F0[q], w1 = F1[q];
        res[q*4+0] += af[ii]*w0.x + ab[ii]*w1.x;
        res[q*4+1] += af[ii]*w0.y + ab[ii]*w1.y;
        res[q*4+2] += af[ii]*w0.z + ab[ii]*w1.z;
        res[q*4+3] += af[ii]*w0.w + ab[ii]*w1.w;
      }
    }
  }
  #pragma unroll
  for(int c = 0; c < 32; ++c) res_s[f][cbase + c] = res[c];
  __syncthreads();
  {
    const int fi = tid & 127, cq = tid >> 7;
    for(int c = cq*32; c < cq*32 + 32; ++c)
      out[(size_t)c*32768 + (size_t)t*128 + fi] = res_s[fi][c];
  }
}

// ---------------------------------------------------------------------------
extern "C" void kernel_launch(void* const* d_in, const int* in_sizes, int n_in,
                              void* d_out, int out_size, void* d_ws, size_t ws_size,
                              hipStream_t stream){
  (void)in_sizes; (void)n_in; (void)out_size; (void)ws_size;
  const float* x         = (const float*)d_in[0];
  const float* norm_w    = (const float*)d_in[1];
  const float* in_proj_w = (const float*)d_in[2];
  const float* conv_w    = (const float*)d_in[3];
  const float* conv_b    = (const float*)d_in[4];
  const float* x_proj_w  = (const float*)d_in[5];
  const float* dt_proj_w = (const float*)d_in[6];
  const float* dt_proj_b = (const float*)d_in[7];
  const float* A_log     = (const float*)d_in[8];
  const float* Dp        = (const float*)d_in[9];
  const float* out_proj_w= (const float*)d_in[10];
  const float* tlin_w    = (const float*)d_in[11];
  const float* tlin_b    = (const float*)d_in[12];
  const float* flin_w    = (const float*)d_in[13];
  const float* flin_b    = (const float*)d_in[14];
  float* out = (float*)d_out;

  float* xt_buf = (float*)d_ws;                 // 2M floats  (8 MB)   [f][t][c]
  float* obuf   = xt_buf + (size_t)(1u << 21);  // 4M floats  (16 MB)  [dir][token][64]
  float* xt2    = obuf   + (size_t)(1u << 22);  // 2M floats  (8 MB)   [f][t][c]

  // bf16 weights live at the START of d_out (used as scratch; k_final fully
  // overwrites d_out at the end of every launch).
  unsigned short* wbf = (unsigned short*)d_out;

  hipLaunchKernelGGL(k_prep, dim3(384), dim3(256), 0, stream,
      in_proj_w, out_proj_w, wbf);

  hipLaunchKernelGGL(k_transpose_in, dim3(256), dim3(256), 0, stream, x, xt_buf);

  // time axis: N=128 sequences (f), L=256 (t); params P0 (fwd), P1 (bwd)
  hipLaunchKernelGGL(k_mamba, dim3(256), dim3(256), 0, stream,
      xt_buf, 128, 256, (long long)16384, (long long)64, 0,
      norm_w, wbf, conv_w, conv_b, x_proj_w, dt_proj_w, dt_proj_b,
      A_log, Dp, obuf);

  hipLaunchKernelGGL(k_comb_time, dim3(8192), dim3(256), 0, stream,
      xt_buf, obuf, tlin_w, tlin_b, xt2);

  // freq axis: N=256 sequences (t), L=128 (f); params P2 (fwd), P3 (bwd)
  hipLaunchKernelGGL(k_mamba, dim3(512), dim3(256), 0, stream,
      xt2, 256, 128, (long long)64, (long long)16384, 2,
      norm_w, wbf, conv_w, conv_b, x_proj_w, dt_proj_w, dt_proj_b,
      A_log, Dp, obuf);

  hipLaunchKernelGGL(k_final, dim3(256), dim3(256), 0, stream,
      xt2, obuf, flin_w, flin_b, out);
}

// Round 10
// 431.309 us; speedup vs baseline: 1.7668x; 1.1611x over previous
//
#include <hip/hip_runtime.h>
#include <math.h>

// Problem constants
#define C_DIM 64
#define T_DIM 256
#define F_DIM 128
#define DI    128
#define DS    16
#define CK    16     // tokens per chunk in fused mamba kernel

typedef __attribute__((ext_vector_type(8))) short bf16x8;  // 8 bf16 = 4 VGPRs
typedef __attribute__((ext_vector_type(4))) float f32x4;   // MFMA C/D

__device__ __forceinline__ float silu_f(float v){ return v / (1.0f + __expf(-v)); }

__device__ __forceinline__ unsigned short f2bf(float f){
  union{float f; unsigned u;} v; v.f = f;
  unsigned r = v.u + 0x7FFFu + ((v.u >> 16) & 1u);   // RTNE
  return (unsigned short)(r >> 16);
}

// ---------------------------------------------------------------------------
// bf16 weight prep into d_out scratch (fully overwritten by k_final later):
//   [0,65536)        in_proj   [4][256][64]
//   [65536,98304)    out_proj  [4][64][128]
//   [98304,122880)   x_proj    [4][48][128]  rows 36..47 zero-padded
//   [122880,131072)  tlin^T    [64][128]     TL[o][i] = tlin_w[i][o]
// ---------------------------------------------------------------------------
__global__ __launch_bounds__(256) void k_prep(const float* __restrict__ ipw,
                                              const float* __restrict__ opw,
                                              const float* __restrict__ xpw,
                                              const float* __restrict__ tlw,
                                              unsigned short* __restrict__ wbuf){
  const int i = blockIdx.x*256 + threadIdx.x;
  if(i < 65536){
    wbuf[i] = f2bf(ipw[i]);
  } else if(i < 98304){
    wbuf[i] = f2bf(opw[i - 65536]);
  } else if(i < 122880){
    const int j = i - 98304;
    const int p = j / 6144, rr = (j - p*6144) >> 7, k = j & 127;
    wbuf[i] = (rr < 36) ? f2bf(xpw[p*4608 + rr*128 + k]) : (unsigned short)0;
  } else { // i < 131072
    const int j = i - 122880;
    const int o = j >> 7, k = j & 127;
    wbuf[i] = f2bf(tlw[k*64 + o]);
  }
}

// ---------------------------------------------------------------------------
// x (1,64,256,128) [c,t,f] -> xt (f,t,c), one block per t
// ---------------------------------------------------------------------------
__global__ __launch_bounds__(256) void k_transpose_in(const float* __restrict__ x,
                                                      float* __restrict__ xt){
  __shared__ float tile[64][133];
  const int t = blockIdx.x;
  {
    const int fi = threadIdx.x & 127, cg = threadIdx.x >> 7;  // cg 0..1
    for(int c = cg*32; c < cg*32 + 32; ++c)
      tile[c][fi] = x[(size_t)c*32768 + (size_t)t*128 + fi];
  }
  __syncthreads();
  {
    const int ci = threadIdx.x & 63, fg = threadIdx.x >> 6;   // fg 0..3
    for(int f = fg*32; f < fg*32 + 32; ++f)
      xt[(size_t)f*16384 + (size_t)t*64 + ci] = tile[ci][f];
  }
}

// ---------------------------------------------------------------------------
// Fused per-sequence Mamba mixer. One workgroup = (dir, sequence n).
// in_proj / x_proj / out_proj on bf16 MFMA (weights in wbf);
// conv / dt_proj / scan / gating stay fp32 VALU.
// ---------------------------------------------------------------------------
__global__ __launch_bounds__(256, 2) void k_mamba(
    const float* __restrict__ src, int N, int L, long long sn, long long sl,
    int pbase,
    const float* __restrict__ norm_w,   const unsigned short* __restrict__ wbf,
    const float* __restrict__ conv_w,   const float* __restrict__ conv_b,
    const float* __restrict__ dt_proj_w,
    const float* __restrict__ dt_proj_b,const float* __restrict__ A_log,
    const float* __restrict__ Dp,       float* __restrict__ obuf)
{
  __shared__ __align__(16) unsigned short u_bf[CK][64];   // normalized input, bf16
  __shared__ float x_s[CK+3][132];     // conv input, rows 0..2 = history
  __shared__ float z_s[CK][132];       // gate
  __shared__ float xc_s[CK][132];      // conv out fp32 (scan input)
  __shared__ __align__(16) unsigned short xc_bf[CK][128]; // conv out bf16 (P4 MFMA B)
  __shared__ float dt_s[CK][132];
  __shared__ float dtr_s[CK][4];
  __shared__ float B_s[CK][20];
  __shared__ float C_s[CK][20];
  __shared__ __align__(16) unsigned short y_bf[CK][128];  // gated y, bf16 (P8 input)
  __shared__ float y_out[CK][68];      // out_proj result
  __shared__ float w_cv[512];
  __shared__ float b_cv[128];
  __shared__ float w_dt[512];
  __shared__ float b_dt[128];
  __shared__ float dvec[128];
  __shared__ float nw[64];

  const int tid = threadIdx.x;
  const int bid = blockIdx.x;
  const int dir = (bid >= N) ? 1 : 0;
  const int n   = dir ? (bid - N) : bid;
  const int p   = pbase + dir;

  const int lane = tid & 63;
  const int wv   = tid >> 6;          // wave 0..3
  const int fr   = lane & 15;         // fragment row/col (token or o within tile)
  const int fk   = (lane >> 4) << 3;  // k-offset within 32-slice: {0,8,16,24}

  // stage small fp32 params into LDS
  for(int i = tid; i < 512; i += 256){ w_cv[i] = conv_w[p*512 + i]; w_dt[i] = dt_proj_w[p*512 + i]; }
  if(tid < 128){ b_cv[tid] = conv_b[p*128 + tid]; b_dt[tid] = dt_proj_b[p*128 + tid]; dvec[tid] = Dp[p*128 + tid]; }
  if(tid < 64) nw[tid] = norm_w[p*64 + tid];
  for(int i = tid; i < 3*128; i += 256){ x_s[i >> 7][i & 127] = 0.0f; }  // zero conv history

  // MFMA weight fragments (registers, whole kernel).
  const unsigned short* WinB  = wbf + (size_t)p*16384;          // [256][64]
  const unsigned short* WoutB = wbf + 65536 + (size_t)p*8192;   // [64][128]
  const unsigned short* XpB   = wbf + 98304 + (size_t)p*6144;   // [48][128]
  bf16x8 aW[4][2];
  #pragma unroll
  for(int ot = 0; ot < 4; ++ot)
    #pragma unroll
    for(int kh = 0; kh < 2; ++kh)
      aW[ot][kh] = *(const bf16x8*)(WinB + (wv*64 + ot*16 + fr)*64 + kh*32 + fk);
  bf16x8 aO[4];
  #pragma unroll
  for(int kc = 0; kc < 4; ++kc)
    aO[kc] = *(const bf16x8*)(WoutB + (wv*16 + fr)*128 + kc*32 + fk);
  bf16x8 aXP[4];
  if(wv < 3){
    #pragma unroll
    for(int kc = 0; kc < 4; ++kc)
      aXP[kc] = *(const bf16x8*)(XpB + (wv*16 + fr)*128 + kc*32 + fk);
  }

  // scan state: thread pair per channel d; each thread owns 8 of 16 states
  const int d_own = tid >> 1;
  const int sh    = (tid & 1) * 8;
  float A_r[8], h[8];
  #pragma unroll
  for(int i = 0; i < 8; ++i){
    A_r[i] = -__expf(A_log[p*2048 + d_own*16 + sh + i]) * 1.44269504f;  // A * log2(e)
    h[i] = 0.0f;
  }
  __syncthreads();

  for(int c0 = 0; c0 < L; c0 += CK){
    // P9: shift conv history (rows CK..CK+2 of previous chunk -> rows 0..2)
    if(c0 > 0){
      for(int i = tid; i < 3*128; i += 256){
        int r = i >> 7, ch = i & 127;
        x_s[r][ch] = x_s[CK + r][ch];
      }
    }
    // P1: load + rmsnorm -> u_bf (bf16). 16 tokens x 16 threads, 4 ch each.
    {
      const int g = tid >> 4, j = tid & 15, c4 = j*4;
      const int l = c0 + g;
      const int lo = dir ? (L - 1 - l) : l;
      const float4 v = *(const float4*)(src + (size_t)n*sn + (size_t)lo*sl + c4);
      float ssq = v.x*v.x + v.y*v.y + v.z*v.z + v.w*v.w;
      ssq += __shfl_xor(ssq, 1); ssq += __shfl_xor(ssq, 2);
      ssq += __shfl_xor(ssq, 4); ssq += __shfl_xor(ssq, 8);
      const float sc = rsqrtf(ssq * (1.0f/64.0f) + 1e-5f);
      ushort4 pk;
      pk.x = f2bf(v.x * sc * nw[c4+0]);
      pk.y = f2bf(v.y * sc * nw[c4+1]);
      pk.z = f2bf(v.z * sc * nw[c4+2]);
      pk.w = f2bf(v.w * sc * nw[c4+3]);
      *(ushort4*)&u_bf[g][c4] = pk;
    }
    __syncthreads();

    // P2: in_proj 64 -> 256 via MFMA. D: row=(lane>>4)*4+r (o), col=fr (token).
    {
      const bf16x8 b0 = *(const bf16x8*)&u_bf[fr][fk];
      const bf16x8 b1 = *(const bf16x8*)&u_bf[fr][32 + fk];
      #pragma unroll
      for(int ot = 0; ot < 4; ++ot){
        f32x4 acc = {0.f, 0.f, 0.f, 0.f};
        acc = __builtin_amdgcn_mfma_f32_16x16x32_bf16(aW[ot][0], b0, acc, 0, 0, 0);
        acc = __builtin_amdgcn_mfma_f32_16x16x32_bf16(aW[ot][1], b1, acc, 0, 0, 0);
        const int ob = wv*64 + ot*16 + ((lane >> 4) << 2);
        if(wv < 2){
          #pragma unroll
          for(int r = 0; r < 4; ++r) x_s[3 + fr][ob + r] = acc[r];
        } else {
          #pragma unroll
          for(int r = 0; r < 4; ++r) z_s[fr][ob + r - 128] = acc[r];
        }
      }
    }
    __syncthreads();

    // P3: causal depthwise conv(4) + bias + silu -> xc_s (fp32) and xc_bf (bf16)
    {
      const int g = tid >> 4, j = tid & 15;
      #pragma unroll
      for(int i = 0; i < 8; ++i){
        const int ch = j + 16*i;
        float a = b_cv[ch];
        a += w_cv[ch*4+0] * x_s[g+0][ch];
        a += w_cv[ch*4+1] * x_s[g+1][ch];
        a += w_cv[ch*4+2] * x_s[g+2][ch];
        a += w_cv[ch*4+3] * x_s[g+3][ch];
        const float s = silu_f(a);
        xc_s[g][ch]  = s;
        xc_bf[g][ch] = f2bf(s);
      }
    }
    __syncthreads();

    // P4: x_proj 128 -> 36 via MFMA (waves 0..2; tile wv covers o36 = 16wv..16wv+15)
    if(wv < 3){
      f32x4 acc = {0.f, 0.f, 0.f, 0.f};
      #pragma unroll
      for(int kc = 0; kc < 4; ++kc){
        const bf16x8 b = *(const bf16x8*)&xc_bf[fr][kc*32 + fk];
        acc = __builtin_amdgcn_mfma_f32_16x16x32_bf16(aXP[kc], b, acc, 0, 0, 0);
      }
      const int ob36 = wv*16 + ((lane >> 4) << 2);
      #pragma unroll
      for(int r = 0; r < 4; ++r){
        const int o36 = ob36 + r;
        const float v = acc[r];
        if(o36 < 4)       dtr_s[fr][o36] = v;
        else if(o36 < 20) B_s[fr][o36 - 4] = v;
        else if(o36 < 36) C_s[fr][o36 - 20] = v;
      }
    }
    __syncthreads();

    // P5: dt_proj 4 -> 128 + bias + softplus
    {
      const int g = tid >> 4, j = tid & 15;
      const float r0 = dtr_s[g][0], r1 = dtr_s[g][1], r2 = dtr_s[g][2], r3 = dtr_s[g][3];
      #pragma unroll
      for(int i = 0; i < 8; ++i){
        const int d = j + 16*i;
        float a = b_dt[d] + w_dt[d*4+0]*r0 + w_dt[d*4+1]*r1 + w_dt[d*4+2]*r2 + w_dt[d*4+3]*r3;
        dt_s[g][d] = fmaxf(a, 0.0f) + log1pf(__expf(-fabsf(a)));  // stable softplus
      }
    }
    __syncthreads();

    // P6: sequential selective scan over the chunk (no barriers inside).
    for(int l = 0; l < CK; ++l){
      const float dtv = dt_s[l][d_own];
      const float xv  = xc_s[l][d_own];
      const float4 b0 = *(const float4*)&B_s[l][sh];
      const float4 b1 = *(const float4*)&B_s[l][sh + 4];
      const float4 g0 = *(const float4*)&C_s[l][sh];
      const float4 g1 = *(const float4*)&C_s[l][sh + 4];
      const float bb[8] = {b0.x,b0.y,b0.z,b0.w,b1.x,b1.y,b1.z,b1.w};
      const float cc[8] = {g0.x,g0.y,g0.z,g0.w,g1.x,g1.y,g1.z,g1.w};
      const float dx = dtv * xv;
      float yp = 0.0f;
      #pragma unroll
      for(int i = 0; i < 8; ++i){
        h[i] = exp2f(dtv * A_r[i]) * h[i] + dx * bb[i];
        yp += h[i] * cc[i];
      }
      const float yo = yp + __shfl_xor(yp, 1);
      if((tid & 1) == 0) xc_s[l][d_own] = yo + xv * dvec[d_own];
    }
    __syncthreads();

    // P7: y = y * silu(z) -> y_bf (bf16, input of out_proj MFMA)
    {
      const int g = tid >> 4, j = tid & 15;
      #pragma unroll
      for(int i = 0; i < 8; ++i){
        const int ch = j + 16*i;
        y_bf[g][ch] = f2bf(xc_s[g][ch] * silu_f(z_s[g][ch]));
      }
    }
    __syncthreads();

    // P8: out_proj 128 -> 64 via MFMA. wave wv -> o2-tile wv.
    {
      f32x4 acc = {0.f, 0.f, 0.f, 0.f};
      #pragma unroll
      for(int kc = 0; kc < 4; ++kc){
        const bf16x8 b = *(const bf16x8*)&y_bf[fr][kc*32 + fk];
        acc = __builtin_amdgcn_mfma_f32_16x16x32_bf16(aO[kc], b, acc, 0, 0, 0);
      }
      const int o2 = wv*16 + ((lane >> 4) << 2);
      #pragma unroll
      for(int r = 0; r < 4; ++r) y_out[fr][o2 + r] = acc[r];
    }
    __syncthreads();

    // P8b: coalesced store to obuf (logical/unflipped order)
    {
      const int o = tid & 63, lg = tid >> 6;   // 4 token-groups of 4
      #pragma unroll
      for(int li = 0; li < 4; ++li){
        const int l = c0 + lg*4 + li;
        const int lo = dir ? (L - 1 - l) : l;
        obuf[((size_t)dir*32768 + (size_t)n*L + lo)*64 + o] = y_out[lg*4 + li][o];
      }
    }
    // end-of-chunk barrier elided (touch-sets disjoint; audited r6/r7)
  }
}

// ---------------------------------------------------------------------------
// xt2 = xt + (of+xt)@tlin[0:64] + (ob+xt)@tlin[64:128] + tlin_b  via MFMA.
// 64 tokens per block, 4 waves; wave wv owns o-tile wv; K=128 (f'|b').
// ---------------------------------------------------------------------------
__global__ __launch_bounds__(256) void k_comb_time(
    const float* __restrict__ xt, const float* __restrict__ obuf,
    const unsigned short* __restrict__ wbf, const float* __restrict__ tlin_b,
    float* __restrict__ xt2)
{
  __shared__ __align__(16) unsigned short in_bf[64][128];  // k: 0..63 f', 64..127 b'
  __shared__ float xs[64][72];                             // x residual -> result
  const int tid = threadIdx.x;
  const int lane = tid & 63, wv = tid >> 6;
  const int fr = lane & 15, fk = (lane >> 4) << 3;
  const int tk0 = blockIdx.x*64;

  // A-frags: transposed tlin (bf16) rows o = wv*16 + fr
  const unsigned short* TL = wbf + 122880;
  bf16x8 aT[4];
  #pragma unroll
  for(int kc = 0; kc < 4; ++kc)
    aT[kc] = *(const bf16x8*)(TL + (wv*16 + fr)*128 + kc*32 + fk);

  // staging: thread (tg = token-in-block, q = channel quad)
  {
    const int tg = tid >> 2, q = tid & 3;
    #pragma unroll
    for(int s = 0; s < 4; ++s){
      const int c4 = q*16 + s*4;
      const float4 xv = *(const float4*)(xt   + ((size_t)tk0 + tg)*64 + c4);
      const float4 fv = *(const float4*)(obuf + ((size_t)tk0 + tg)*64 + c4);
      const float4 bv = *(const float4*)(obuf + ((size_t)32768 + tk0 + tg)*64 + c4);
      ushort4 pf, pb;
      pf.x = f2bf(fv.x + xv.x); pf.y = f2bf(fv.y + xv.y);
      pf.z = f2bf(fv.z + xv.z); pf.w = f2bf(fv.w + xv.w);
      pb.x = f2bf(bv.x + xv.x); pb.y = f2bf(bv.y + xv.y);
      pb.z = f2bf(bv.z + xv.z); pb.w = f2bf(bv.w + xv.w);
      *(ushort4*)&in_bf[tg][c4]      = pf;
      *(ushort4*)&in_bf[tg][64 + c4] = pb;
      *(float4*)&xs[tg][c4] = xv;
    }
  }
  __syncthreads();

  // MFMA: wave wv, token-tiles tt=0..3; in-place result into xs
  {
    const int ob = wv*16 + ((lane >> 4) << 2);
    const float4 tb = *(const float4*)(tlin_b + ob);
    const float tbr[4] = {tb.x, tb.y, tb.z, tb.w};
    #pragma unroll
    for(int tt = 0; tt < 4; ++tt){
      f32x4 acc = {0.f, 0.f, 0.f, 0.f};
      #pragma unroll
      for(int kc = 0; kc < 4; ++kc){
        const bf16x8 b = *(const bf16x8*)&in_bf[tt*16 + fr][kc*32 + fk];
        acc = __builtin_amdgcn_mfma_f32_16x16x32_bf16(aT[kc], b, acc, 0, 0, 0);
      }
      const int token = tt*16 + fr;
      #pragma unroll
      for(int r = 0; r < 4; ++r)
        xs[token][ob + r] += tbr[r] + acc[r];   // lane-exclusive (token,o)
    }
  }
  __syncthreads();

  // coalesced store
  {
    const int tg = tid >> 2, q = tid & 3;
    #pragma unroll
    for(int s = 0; s < 4; ++s){
      const int c4 = q*16 + s*4;
      *(float4*)(xt2 + ((size_t)tk0 + tg)*64 + c4) = *(const float4*)&xs[tg][c4];
    }
  }
}

// ---------------------------------------------------------------------------
// Final: xf2 = xf + (of+xf)@flin[0:64] + (ob+xf)@flin[64:128] + flin_b,
// then transposed store out[c,t,f]. One block per t; thread pair per f.
// ---------------------------------------------------------------------------
__global__ __launch_bounds__(256) void k_final(
    const float* __restrict__ xt2, const float* __restrict__ obuf,
    const float* __restrict__ flin_w, const float* __restrict__ flin_b,
    float* __restrict__ out)
{
  __shared__ float res_s[128][68];
  const int t = blockIdx.x, tid = threadIdx.x;
  const int f = tid >> 1, half = tid & 1, cbase = half*32;

  const float4* xr = (const float4*)(xt2  + (size_t)f*16384 + (size_t)t*64);
  const float4* fr = (const float4*)(obuf + ((size_t)t*128 + f)*64);
  const float4* br = (const float4*)(obuf + ((size_t)32768 + (size_t)t*128 + f)*64);

  float res[32];
  {
    const float4* fb = (const float4*)(flin_b + cbase);
    #pragma unroll
    for(int q = 0; q < 8; ++q){
      const float4 xv = xr[(cbase >> 2) + q], b = fb[q];
      res[q*4+0] = xv.x + b.x; res[q*4+1] = xv.y + b.y;
      res[q*4+2] = xv.z + b.z; res[q*4+3] = xv.w + b.w;
    }
  }
  for(int i4 = 0; i4 < 16; ++i4){
    const float4 xv4 = xr[i4], of4 = fr[i4], ob4 = br[i4];
    const float af[4] = {of4.x + xv4.x, of4.y + xv4.y, of4.z + xv4.z, of4.w + xv4.w};
    const float ab[4] = {ob4.x + xv4.x, ob4.y + xv4.y, ob4.z + xv4.z, ob4.w + xv4.w};
    #pragma unroll
    for(int ii = 0; ii < 4; ++ii){
      const int i = i4*4 + ii;
      const float4* F0 = (const float4*)(flin_w + i*64 + cbase);
      const float4* F1 = (const float4*)(flin_w + (64 + i)*64 + cbase);
      #pragma unroll
      for(int q = 0; q < 8; ++q){
        const float4 w0 = F0[q], w1 = F1[q];
        res[q*4+0] += af[ii]*w0.x + ab[ii]*w1.x;
        res[q*4+1] += af[ii]*w0.y + ab[ii]*w1.y;
        res[q*4+2] += af[ii]*w0.z + ab[ii]*w1.z;
        res[q*4+3] += af[ii]*w0.w + ab[ii]*w1.w;
      }
    }
  }
  #pragma unroll
  for(int c = 0; c < 32; ++c) res_s[f][cbase + c] = res[c];
  __syncthreads();
  {
    const int fi = tid & 127, cq = tid >> 7;
    for(int c = cq*32; c < cq*32 + 32; ++c)
      out[(size_t)c*32768 + (size_t)t*128 + fi] = res_s[fi][c];
  }
}

// ---------------------------------------------------------------------------
extern "C" void kernel_launch(void* const* d_in, const int* in_sizes, int n_in,
                              void* d_out, int out_size, void* d_ws, size_t ws_size,
                              hipStream_t stream){
  (void)in_sizes; (void)n_in; (void)out_size; (void)ws_size;
  const float* x         = (const float*)d_in[0];
  const float* norm_w    = (const float*)d_in[1];
  const float* in_proj_w = (const float*)d_in[2];
  const float* conv_w    = (const float*)d_in[3];
  const float* conv_b    = (const float*)d_in[4];
  const float* x_proj_w  = (const float*)d_in[5];
  const float* dt_proj_w = (const float*)d_in[6];
  const float* dt_proj_b = (const float*)d_in[7];
  const float* A_log     = (const float*)d_in[8];
  const float* Dp        = (const float*)d_in[9];
  const float* out_proj_w= (const float*)d_in[10];
  const float* tlin_w    = (const float*)d_in[11];
  const float* tlin_b    = (const float*)d_in[12];
  const float* flin_w    = (const float*)d_in[13];
  const float* flin_b    = (const float*)d_in[14];
  float* out = (float*)d_out;

  float* xt_buf = (float*)d_ws;                 // 2M floats  (8 MB)   [f][t][c]
  float* obuf   = xt_buf + (size_t)(1u << 21);  // 4M floats  (16 MB)  [dir][token][64]
  float* xt2    = obuf   + (size_t)(1u << 22);  // 2M floats  (8 MB)   [f][t][c]

  // bf16 weights at the START of d_out (scratch; k_final overwrites d_out).
  unsigned short* wbf = (unsigned short*)d_out;

  hipLaunchKernelGGL(k_prep, dim3(512), dim3(256), 0, stream,
      in_proj_w, out_proj_w, x_proj_w, tlin_w, wbf);

  hipLaunchKernelGGL(k_transpose_in, dim3(256), dim3(256), 0, stream, x, xt_buf);

  // time axis: N=128 sequences (f), L=256 (t); params P0 (fwd), P1 (bwd)
  hipLaunchKernelGGL(k_mamba, dim3(256), dim3(256), 0, stream,
      xt_buf, 128, 256, (long long)16384, (long long)64, 0,
      norm_w, wbf, conv_w, conv_b, dt_proj_w, dt_proj_b,
      A_log, Dp, obuf);

  hipLaunchKernelGGL(k_comb_time, dim3(512), dim3(256), 0, stream,
      xt_buf, obuf, wbf, tlin_b, xt2);

  // freq axis: N=256 sequences (t), L=128 (f); params P2 (fwd), P3 (bwd)
  hipLaunchKernelGGL(k_mamba, dim3(512), dim3(256), 0, stream,
      xt2, 256, 128, (long long)64, (long long)16384, 2,
      norm_w, wbf, conv_w, conv_b, dt_proj_w, dt_proj_b,
      A_log, Dp, obuf);

  hipLaunchKernelGGL(k_final, dim3(256), dim3(256), 0, stream,
      xt2, obuf, flin_w, flin_b, out);
}